// Round 8
// baseline (288.080 us; speedup 1.0000x reference)
//
#include <hip/hip_runtime.h>
#include <hip/hip_bf16.h>

#define B_ 4
#define N_ 10000
#define E_ 160000
#define D_ 128
#define H_ 4
#define HID_ 128
#define DK_ 32
#define DE_ 16

typedef __attribute__((ext_vector_type(8))) short short8v;
typedef __attribute__((ext_vector_type(4))) short short4v;
typedef __attribute__((ext_vector_type(4))) float f32x4;

// fp32 -> bf16 bits, round-to-nearest-even
__device__ __forceinline__ short bfb(float f) {
  union { float f; unsigned u; } c; c.f = f;
  unsigned u = c.u + 0x7FFFu + ((c.u >> 16) & 1u);
  return (short)(u >> 16);
}
// bf16 bits -> fp32
__device__ __forceinline__ float b2f(unsigned short u) {
  union { unsigned u; float f; } c; c.u = ((unsigned)u) << 16;
  return c.f;
}

// ---------------------------------------------------------------------------
// P0: W^T bf16 prep. wt[m][n][k] = bf16(W_m[k*128+n]),  m: 0=q 1=k 2=v 3=o
// ---------------------------------------------------------------------------
__global__ __launch_bounds__(256) void wt_prep(
    const float* __restrict__ Wq, const float* __restrict__ Wk,
    const float* __restrict__ Wv, const float* __restrict__ Wo,
    short* __restrict__ wt) {
  const float* Ws[4] = {Wq, Wk, Wv, Wo};
  const int i = blockIdx.x * 256 + threadIdx.x;   // 0..65535
  const int m = i >> 14;
  const int k = (i >> 7) & 127;
  const int n = i & 127;
  wt[(size_t)m * 16384 + n * 128 + k] = bfb(Ws[m][k * 128 + n]);
}

// ---------------------------------------------------------------------------
// K1: QKV projection via MFMA. block = 256 (4 waves), 64 rows/block.
// Q -> fp32 [b][n][128]; K,V -> bf16 kv[n][b][0:128 | 128:256]
// ---------------------------------------------------------------------------
__global__ __launch_bounds__(256) void qkv_mfma(
    const float* __restrict__ x, const short* __restrict__ wt,
    const float* __restrict__ bq, const float* __restrict__ bk,
    const float* __restrict__ bv,
    float* __restrict__ Q, short* __restrict__ kv) {
  __shared__ short xs[64][136];
  const int tid  = threadIdx.x;
  const int lane = tid & 63;
  const int wave = tid >> 6;
  const int ln15 = lane & 15;
  const int g    = lane >> 4;
  const long rowBase = (long)blockIdx.x * 64;

  for (int i = tid; i < 64 * 32; i += 256) {
    const int r  = i >> 5;
    const int c4 = (i & 31) * 4;
    const float4 v = *(const float4*)(x + (rowBase + r) * 128 + c4);
    short4v sv; sv.x = bfb(v.x); sv.y = bfb(v.y); sv.z = bfb(v.z); sv.w = bfb(v.w);
    *(short4v*)&xs[r][c4] = sv;
  }
  __syncthreads();

  short8v af[4];
#pragma unroll
  for (int kk = 0; kk < 4; ++kk)
    af[kk] = *(const short8v*)&xs[wave * 16 + ln15][kk * 32 + g * 8];

  const float* bs[3] = {bq, bk, bv};

#pragma unroll
  for (int m = 0; m < 3; ++m) {
    const short* Wt = wt + (size_t)m * 16384;
    f32x4 acc[8];
#pragma unroll
    for (int cb = 0; cb < 8; ++cb) acc[cb] = (f32x4){0.f, 0.f, 0.f, 0.f};

#pragma unroll
    for (int kk = 0; kk < 4; ++kk) {
#pragma unroll
      for (int cb = 0; cb < 8; ++cb) {
        const short8v bfr =
            *(const short8v*)(Wt + (cb * 16 + ln15) * 128 + kk * 32 + g * 8);
        acc[cb] = __builtin_amdgcn_mfma_f32_16x16x32_bf16(af[kk], bfr, acc[cb], 0, 0, 0);
      }
    }

    const float* bias = bs[m];
#pragma unroll
    for (int cb = 0; cb < 8; ++cb) {
      const int col = cb * 16 + ln15;
      const float bv_ = bias[col];
#pragma unroll
      for (int r = 0; r < 4; ++r) {
        const long row = rowBase + wave * 16 + g * 4 + r;
        const float val = acc[cb][r] + bv_;
        if (m == 0) {
          Q[row * 128 + col] = val;
        } else {
          const int bb = (int)(row / N_);
          const int nn = (int)(row - (long)bb * N_);
          kv[((size_t)nn * 4 + bb) * 256 + (m - 1) * 128 + col] = bfb(val);
        }
      }
    }
  }
}

// ---------------------------------------------------------------------------
// CSR build
// ---------------------------------------------------------------------------
__global__ __launch_bounds__(256) void csr_hist(const int* __restrict__ ei,
                                                int* __restrict__ cnt) {
  const int e = blockIdx.x * 256 + threadIdx.x;
  if (e < E_) atomicAdd(&cnt[ei[E_ + e]], 1);
}

__global__ __launch_bounds__(1024) void csr_scan(const int* __restrict__ cnt,
                                                 int* __restrict__ rowptr,
                                                 int* __restrict__ fill) {
  __shared__ int part[1024];
  const int t = threadIdx.x;
  int local[10];
  int sum = 0;
#pragma unroll
  for (int i = 0; i < 10; ++i) {
    const int idx = t * 10 + i;
    local[i] = sum;
    sum += (idx < N_) ? cnt[idx] : 0;
  }
  part[t] = sum;
  __syncthreads();
  for (int off = 1; off < 1024; off <<= 1) {
    const int v = (t >= off) ? part[t - off] : 0;
    __syncthreads();
    part[t] += v;
    __syncthreads();
  }
  const int excl = (t == 0) ? 0 : part[t - 1];
#pragma unroll
  for (int i = 0; i < 10; ++i) {
    const int idx = t * 10 + i;
    if (idx <= N_) {
      const int o = excl + local[i];
      rowptr[idx] = o;
      if (idx < N_) fill[idx] = o;
    }
  }
}

// scatter: CSR-ordered src + CSR-ordered copy of edge_attr
__global__ __launch_bounds__(256) void csr_scatter(
    const int* __restrict__ ei, const float* __restrict__ ea,
    int* __restrict__ fill, int* __restrict__ esrc, float* __restrict__ eas) {
  const int e = blockIdx.x * 256 + threadIdx.x;
  if (e < E_) {
    const int dst = ei[E_ + e];
    const int pos = atomicAdd(&fill[dst], 1);
    esrc[pos] = ei[e];
    const float4* s4 = (const float4*)(ea + (size_t)e * 16);
    float4* d4 = (float4*)(eas + (size_t)pos * 16);
    d4[0] = s4[0]; d4[1] = s4[1]; d4[2] = s4[2]; d4[3] = s4[3];
  }
}

// ---------------------------------------------------------------------------
// P1: FiLM precompute.  film[i][0:128] = 1+gamma (bf16), [128:256] = beta.
// block = 256 threads = 8 edges; thread -> (edge = tid>>5, cols = (tid&31)*8).
// ---------------------------------------------------------------------------
__global__ __launch_bounds__(256) void film_prep(
    const float* __restrict__ eas, const float* __restrict__ Wf,
    const float* __restrict__ bf, short* __restrict__ film) {
  const int e  = blockIdx.x * 8 + (threadIdx.x >> 5);
  const int c0 = (threadIdx.x & 31) * 8;

  const float* ep = eas + (size_t)e * 16;
  float ev[16];
#pragma unroll
  for (int j4 = 0; j4 < 4; ++j4) {
    const float4 t = *(const float4*)(ep + j4 * 4);
    ev[j4 * 4 + 0] = t.x; ev[j4 * 4 + 1] = t.y;
    ev[j4 * 4 + 2] = t.z; ev[j4 * 4 + 3] = t.w;
  }

  float o[8];
  {
    const float4 b0 = *(const float4*)(bf + c0);
    const float4 b1 = *(const float4*)(bf + c0 + 4);
    const float one = (c0 < 128) ? 1.f : 0.f;
    o[0]=b0.x+one; o[1]=b0.y+one; o[2]=b0.z+one; o[3]=b0.w+one;
    o[4]=b1.x+one; o[5]=b1.y+one; o[6]=b1.z+one; o[7]=b1.w+one;
  }
#pragma unroll
  for (int j = 0; j < 16; ++j) {
    const float4 w0 = *(const float4*)(Wf + j * 256 + c0);
    const float4 w1 = *(const float4*)(Wf + j * 256 + c0 + 4);
    o[0] = fmaf(ev[j], w0.x, o[0]);
    o[1] = fmaf(ev[j], w0.y, o[1]);
    o[2] = fmaf(ev[j], w0.z, o[2]);
    o[3] = fmaf(ev[j], w0.w, o[3]);
    o[4] = fmaf(ev[j], w1.x, o[4]);
    o[5] = fmaf(ev[j], w1.y, o[5]);
    o[6] = fmaf(ev[j], w1.z, o[6]);
    o[7] = fmaf(ev[j], w1.w, o[7]);
  }
  short8v sv;
#pragma unroll
  for (int d = 0; d < 8; ++d) sv[d] = bfb(o[d]);
  *(short8v*)(film + (size_t)e * 256 + c0) = sv;
}

// ---------------------------------------------------------------------------
// K2 (new): fused logits + softmax + aggregation, zero shuffles per edge.
// wave per node (block = 4 waves = 4 nodes); lane = e4*16 + b*4 + h.
// Lane owns the FULL 32-dim head dot in-register: q[32] VGPRs,
// k/g/beta/v as 16B bf16 chunks. Lane processes edges beg+e4, beg+e4+4, ...
// End-of-node: acc/se reduced over the 4 e4-slots (shfl_xor 16,32 only).
// Single-pass softmax (no max): logits are O(0.05).
// ---------------------------------------------------------------------------
__global__ __launch_bounds__(256) void fused_attn(
    const int* __restrict__ rowptr, const int* __restrict__ esrc,
    const short* __restrict__ film, const float* __restrict__ Q,
    const short* __restrict__ kv, float* __restrict__ agg) {
  const int node = blockIdx.x * 4 + (threadIdx.x >> 6);
  const int lane = threadIdx.x & 63;
  const int e4 = lane >> 4;
  const int b  = (lane >> 2) & 3;
  const int h  = lane & 3;

  const int beg = rowptr[node], end = rowptr[node + 1];

  float q[32];
  {
    const float* qp = Q + ((size_t)b * N_ + node) * 128 + h * 32;
#pragma unroll
    for (int c = 0; c < 8; ++c) {
      const float4 t = *(const float4*)(qp + c * 4);
      q[c * 4 + 0] = t.x; q[c * 4 + 1] = t.y;
      q[c * 4 + 2] = t.z; q[c * 4 + 3] = t.w;
    }
  }
  float acc[32];
#pragma unroll
  for (int d = 0; d < 32; ++d) acc[d] = 0.f;
  float se = 0.f;

  for (int i = beg + e4; i < end; i += 4) {
    const int src = esrc[i];
    const unsigned short* kp =
        (const unsigned short*)(kv + (((size_t)src << 2) + b) * 256) + h * 32;
    const unsigned short* fp =
        (const unsigned short*)(film + (size_t)i * 256) + h * 32;

    float pl = 0.f;
#pragma unroll
    for (int c = 0; c < 4; ++c) {
      const short8v kb = *(const short8v*)(kp + c * 8);
      const short8v gb = *(const short8v*)(fp + c * 8);
      const short8v tb = *(const short8v*)(fp + 128 + c * 8);
#pragma unroll
      for (int j = 0; j < 8; ++j) {
        const float km = fmaf(b2f((unsigned short)kb[j]),
                              b2f((unsigned short)gb[j]),
                              b2f((unsigned short)tb[j]));
        pl = fmaf(q[c * 8 + j], km, pl);
      }
    }
    const float ex = __expf(pl * 0.17677669529663687f);  // 1/sqrt(32)
    se += ex;
#pragma unroll
    for (int c = 0; c < 4; ++c) {
      const short8v vb = *(const short8v*)(kp + 128 + c * 8);
#pragma unroll
      for (int j = 0; j < 8; ++j)
        acc[c * 8 + j] = fmaf(ex, b2f((unsigned short)vb[j]), acc[c * 8 + j]);
    }
  }

  // reduce the 4 e4-slots
#pragma unroll
  for (int d = 0; d < 32; ++d) {
    acc[d] += __shfl_xor(acc[d], 16);
    acc[d] += __shfl_xor(acc[d], 32);
  }
  se += __shfl_xor(se, 16);
  se += __shfl_xor(se, 32);

  if (e4 == 0) {
    const float inv = (end > beg) ? 1.f / se : 0.f;
    float* ap = agg + ((size_t)b * N_ + node) * 128 + h * 32;
#pragma unroll
    for (int c = 0; c < 8; ++c) {
      float4 o;
      o.x = acc[c * 4 + 0] * inv; o.y = acc[c * 4 + 1] * inv;
      o.z = acc[c * 4 + 2] * inv; o.w = acc[c * 4 + 3] * inv;
      *(float4*)(ap + c * 4) = o;
    }
  }
}

// ---------------------------------------------------------------------------
// K2 fallback (R6 version, used when ws too small for film): per-edge FiLM
// via shuffles.
// ---------------------------------------------------------------------------
__device__ __forceinline__ void edge_step(
    const float4 ev, const unsigned kkb, const unsigned vvb, const float2 q2,
    const float2* wg, const float2* wb,
    const float bg0, const float bg1, const float bb0, const float bb1,
    float& acc0, float& acc1, float& se) {
  float g0 = ev.x * wg[0].x, g1 = ev.x * wg[0].y;
  float t0 = ev.x * wb[0].x, t1 = ev.x * wb[0].y;
  g0 = fmaf(ev.y, wg[1].x, g0); g1 = fmaf(ev.y, wg[1].y, g1);
  t0 = fmaf(ev.y, wb[1].x, t0); t1 = fmaf(ev.y, wb[1].y, t1);
  g0 = fmaf(ev.z, wg[2].x, g0); g1 = fmaf(ev.z, wg[2].y, g1);
  t0 = fmaf(ev.z, wb[2].x, t0); t1 = fmaf(ev.z, wb[2].y, t1);
  g0 = fmaf(ev.w, wg[3].x, g0); g1 = fmaf(ev.w, wg[3].y, g1);
  t0 = fmaf(ev.w, wb[3].x, t0); t1 = fmaf(ev.w, wb[3].y, t1);
  g0 += __shfl_xor(g0, 1); g1 += __shfl_xor(g1, 1);
  t0 += __shfl_xor(t0, 1); t1 += __shfl_xor(t1, 1);
  g0 += __shfl_xor(g0, 2); g1 += __shfl_xor(g1, 2);
  t0 += __shfl_xor(t0, 2); t1 += __shfl_xor(t1, 2);
  g0 += bg0; g1 += bg1;
  t0 += bb0; t1 += bb1;
  const float k0 = __uint_as_float(kkb << 16);
  const float k1 = __uint_as_float(kkb & 0xffff0000u);
  const float v0 = __uint_as_float(vvb << 16);
  const float v1 = __uint_as_float(vvb & 0xffff0000u);
  float pl = fmaf(q2.x, fmaf(k0, g0, t0), q2.y * fmaf(k1, g1, t1));
  pl += __shfl_xor(pl, 4);
  pl += __shfl_xor(pl, 8);
  pl += __shfl_xor(pl, 16);
  pl += __shfl_xor(pl, 32);
  const float ex = __expf(pl * 0.17677669529663687f);
  se += ex;
  acc0 = fmaf(ex, v0, acc0);
  acc1 = fmaf(ex, v1, acc1);
}

__global__ __launch_bounds__(256) void fused_attn_fb(
    const int* __restrict__ rowptr, const int* __restrict__ esrc,
    const float* __restrict__ eas, const float* __restrict__ Wf,
    const float* __restrict__ bf, const float* __restrict__ Q,
    const short* __restrict__ kv, float* __restrict__ agg) {
  const int node = blockIdx.x;
  const int h    = threadIdx.x >> 6;
  const int lane = threadIdx.x & 63;
  const int b    = lane & 3;
  const int p    = lane >> 2;
  const int col0 = h * 32 + 2 * p;

  float2 wg[4], wb[4];
#pragma unroll
  for (int jj = 0; jj < 4; ++jj) {
    wg[jj] = *(const float2*)(Wf + (4 * b + jj) * 256 + col0);
    wb[jj] = *(const float2*)(Wf + (4 * b + jj) * 256 + 128 + col0);
  }
  const float bg0 = 1.f + bf[col0], bg1 = 1.f + bf[col0 + 1];
  const float bb0 = bf[128 + col0], bb1 = bf[129 + col0];

  const float2 q2 = *(const float2*)(Q + ((size_t)b * N_ + node) * 128 + col0);

  const int beg = rowptr[node], end = rowptr[node + 1];
  float acc0 = 0.f, acc1 = 0.f, se = 0.f;
  for (int i = beg; i < end; ++i) {
    const int s0 = esrc[i];
    const float4 e0 = *(const float4*)(eas + (size_t)i * 16 + 4 * b);
    const unsigned* kp0 = (const unsigned*)(kv + (((size_t)s0 << 2) + b) * 256 + col0);
    const unsigned kk0 = kp0[0], vv0 = kp0[64];
    edge_step(e0, kk0, vv0, q2, wg, wb, bg0, bg1, bb0, bb1, acc0, acc1, se);
  }
  const float inv = (end > beg) ? 1.f / se : 0.f;
  float2 o; o.x = acc0 * inv; o.y = acc1 * inv;
  *(float2*)(agg + ((size_t)b * N_ + node) * 128 + col0) = o;
}

// ---------------------------------------------------------------------------
// K4: y = agg @ Wo + bo (MFMA); h = x + y; LayerNorm(h) -> out
// ---------------------------------------------------------------------------
__global__ __launch_bounds__(256) void out_ln_mfma(
    const float* __restrict__ agg, const short* __restrict__ wto,
    const float* __restrict__ bo, const float* __restrict__ x,
    const float* __restrict__ lng, const float* __restrict__ lnb,
    float* __restrict__ out) {
  __shared__ short as_[64][136];
  const int tid  = threadIdx.x;
  const int lane = tid & 63;
  const int wave = tid >> 6;
  const int ln15 = lane & 15;
  const int g    = lane >> 4;
  const long rowBase = (long)blockIdx.x * 64;

  for (int i = tid; i < 64 * 32; i += 256) {
    const int r  = i >> 5;
    const int c4 = (i & 31) * 4;
    const float4 v = *(const float4*)(agg + (rowBase + r) * 128 + c4);
    short4v sv; sv.x = bfb(v.x); sv.y = bfb(v.y); sv.z = bfb(v.z); sv.w = bfb(v.w);
    *(short4v*)&as_[r][c4] = sv;
  }
  __syncthreads();

  short8v af[4];
#pragma unroll
  for (int kk = 0; kk < 4; ++kk)
    af[kk] = *(const short8v*)&as_[wave * 16 + ln15][kk * 32 + g * 8];

  f32x4 acc[8];
#pragma unroll
  for (int cb = 0; cb < 8; ++cb) acc[cb] = (f32x4){0.f, 0.f, 0.f, 0.f};

#pragma unroll
  for (int kk = 0; kk < 4; ++kk) {
#pragma unroll
    for (int cb = 0; cb < 8; ++cb) {
      const short8v bfr =
          *(const short8v*)(wto + (cb * 16 + ln15) * 128 + kk * 32 + g * 8);
      acc[cb] = __builtin_amdgcn_mfma_f32_16x16x32_bf16(af[kk], bfr, acc[cb], 0, 0, 0);
    }
  }

#pragma unroll
  for (int cb = 0; cb < 8; ++cb) {
    const int col = cb * 16 + ln15;
    const float bov = bo[col];
#pragma unroll
    for (int r = 0; r < 4; ++r) {
      const long row = rowBase + wave * 16 + g * 4 + r;
      acc[cb][r] += bov + x[row * 128 + col];
    }
  }

  float s1[4], s2[4];
#pragma unroll
  for (int r = 0; r < 4; ++r) {
    s1[r] = 0.f; s2[r] = 0.f;
#pragma unroll
    for (int cb = 0; cb < 8; ++cb) {
      s1[r] += acc[cb][r];
      s2[r] = fmaf(acc[cb][r], acc[cb][r], s2[r]);
    }
  }
#pragma unroll
  for (int m = 1; m < 16; m <<= 1) {
#pragma unroll
    for (int r = 0; r < 4; ++r) {
      s1[r] += __shfl_xor(s1[r], m);
      s2[r] += __shfl_xor(s2[r], m);
    }
  }
  float mu[4], inv[4];
#pragma unroll
  for (int r = 0; r < 4; ++r) {
    mu[r] = s1[r] * (1.f / 128.f);
    const float var = s2[r] * (1.f / 128.f) - mu[r] * mu[r];
    inv[r] = rsqrtf(var + 1e-5f);
  }

#pragma unroll
  for (int cb = 0; cb < 8; ++cb) {
    const int col = cb * 16 + ln15;
    const float gv = lng[col], bv_ = lnb[col];
#pragma unroll
    for (int r = 0; r < 4; ++r) {
      const long row = rowBase + wave * 16 + g * 4 + r;
      out[row * 128 + col] = (acc[cb][r] - mu[r]) * inv[r] * gv + bv_;
    }
  }
}

// ---------------------------------------------------------------------------
extern "C" void kernel_launch(void* const* d_in, const int* in_sizes, int n_in,
                              void* d_out, int out_size, void* d_ws, size_t ws_size,
                              hipStream_t stream) {
  const float* x   = (const float*)d_in[0];
  const int*   ei  = (const int*)d_in[1];
  const float* ea  = (const float*)d_in[2];
  const float* Wq  = (const float*)d_in[3];
  const float* bq  = (const float*)d_in[4];
  const float* Wk  = (const float*)d_in[5];
  const float* bk  = (const float*)d_in[6];
  const float* Wv  = (const float*)d_in[7];
  const float* bv  = (const float*)d_in[8];
  const float* Wf  = (const float*)d_in[9];
  const float* bf  = (const float*)d_in[10];
  const float* Wo  = (const float*)d_in[11];
  const float* bo  = (const float*)d_in[12];
  const float* lng = (const float*)d_in[13];
  const float* lnb = (const float*)d_in[14];
  float* out = (float*)d_out;

  const size_t NQ = (size_t)B_ * N_ * HID_;  // 5,120,000

  // byte-offset layout (all sections 16B-aligned)
  char* base = (char*)d_ws;
  size_t off = 0;
  float* Q    = (float*)(base + off); off += NQ * 4;                 // 20.48MB
  float* agg  = (float*)(base + off); off += NQ * 4;                 // 20.48MB
  float* eas  = (float*)(base + off); off += (size_t)E_ * 16 * 4;    // 10.24MB
  short* kv   = (short*)(base + off); off += (size_t)B_ * N_ * 256 * 2; // 20.48MB
  short* wt   = (short*)(base + off); off += 4 * 16384 * 2;          // 128KB
  int*  cnt    = (int*)(base + off); off += N_ * 4;
  int*  rowptr = (int*)(base + off); off += (N_ + 1) * 4;
  int*  fill   = (int*)(base + off); off += N_ * 4;
  int*  esrc   = (int*)(base + off); off += E_ * 4;
  off = (off + 15) & ~(size_t)15;
  const size_t base_bytes = off;
  short* film = (short*)(base + off); off += (size_t)E_ * 256 * 2;   // 81.92MB
  const bool use_film = ws_size >= off;

  hipMemsetAsync(cnt, 0, N_ * sizeof(int), stream);

  wt_prep<<<256, 256, 0, stream>>>(Wq, Wk, Wv, Wo, wt);
  qkv_mfma<<<(B_ * N_) / 64, 256, 0, stream>>>(x, wt, bq, bk, bv, Q, kv);
  csr_hist<<<(E_ + 255) / 256, 256, 0, stream>>>(ei, cnt);
  csr_scan<<<1, 1024, 0, stream>>>(cnt, rowptr, fill);
  csr_scatter<<<(E_ + 255) / 256, 256, 0, stream>>>(ei, ea, fill, esrc, eas);
  if (use_film) {
    film_prep<<<E_ / 8, 256, 0, stream>>>(eas, Wf, bf, film);
    fused_attn<<<N_ / 4, 256, 0, stream>>>(rowptr, esrc, film, Q, kv, agg);
  } else {
    fused_attn_fb<<<N_, 256, 0, stream>>>(rowptr, esrc, eas, Wf, bf, Q, kv, agg);
  }
  out_ln_mfma<<<(B_ * N_) / 64, 256, 0, stream>>>(agg, wt + 3 * 16384, bo, x, lng, lnb, out);
  (void)base_bytes;
}

// Round 9
// 214.810 us; speedup vs baseline: 1.3411x; 1.3411x over previous
//
#include <hip/hip_runtime.h>
#include <hip/hip_bf16.h>

#define B_ 4
#define N_ 10000
#define E_ 160000
#define D_ 128
#define H_ 4
#define HID_ 128
#define DK_ 32
#define DE_ 16

typedef __attribute__((ext_vector_type(8))) short short8v;
typedef __attribute__((ext_vector_type(4))) short short4v;
typedef __attribute__((ext_vector_type(4))) float f32x4;
typedef __attribute__((ext_vector_type(2))) float f32x2;

// fp32 -> bf16 bits, round-to-nearest-even
__device__ __forceinline__ short bfb(float f) {
  union { float f; unsigned u; } c; c.f = f;
  unsigned u = c.u + 0x7FFFu + ((c.u >> 16) & 1u);
  return (short)(u >> 16);
}

// fp32 -> fp8 e4m3 (OCP on gfx950), single value via pack instruction
__device__ __forceinline__ unsigned char f2fp8(float f) {
  int r = __builtin_amdgcn_cvt_pk_fp8_f32(f, f, 0, false);
  return (unsigned char)(r & 0xff);
}
// 2 packed fp8 (low 2 bytes of u) -> 2 fp32
__device__ __forceinline__ f32x2 fp8x2f(unsigned short u) {
  return __builtin_amdgcn_cvt_pk_f32_fp8((int)u, false);
}

// ---------------------------------------------------------------------------
// P0: W^T bf16 prep. wt[m][n][k] = bf16(W_m[k*128+n]),  m: 0=q 1=k 2=v 3=o
// ---------------------------------------------------------------------------
__global__ __launch_bounds__(256) void wt_prep(
    const float* __restrict__ Wq, const float* __restrict__ Wk,
    const float* __restrict__ Wv, const float* __restrict__ Wo,
    short* __restrict__ wt) {
  const float* Ws[4] = {Wq, Wk, Wv, Wo};
  const int i = blockIdx.x * 256 + threadIdx.x;   // 0..65535
  const int m = i >> 14;
  const int k = (i >> 7) & 127;
  const int n = i & 127;
  wt[(size_t)m * 16384 + n * 128 + k] = bfb(Ws[m][k * 128 + n]);
}

// ---------------------------------------------------------------------------
// K1: QKV projection via MFMA. block = 256 (4 waves), 64 rows/block.
// Q -> fp32 [b][n][128]; K,V -> fp8 e4m3 kv8[n][b][0:128 = K | 128:256 = V]
// ---------------------------------------------------------------------------
__global__ __launch_bounds__(256) void qkv_mfma(
    const float* __restrict__ x, const short* __restrict__ wt,
    const float* __restrict__ bq, const float* __restrict__ bk,
    const float* __restrict__ bv,
    float* __restrict__ Q, unsigned char* __restrict__ kv8) {
  __shared__ short xs[64][136];
  const int tid  = threadIdx.x;
  const int lane = tid & 63;
  const int wave = tid >> 6;
  const int ln15 = lane & 15;
  const int g    = lane >> 4;
  const long rowBase = (long)blockIdx.x * 64;

  for (int i = tid; i < 64 * 32; i += 256) {
    const int r  = i >> 5;
    const int c4 = (i & 31) * 4;
    const float4 v = *(const float4*)(x + (rowBase + r) * 128 + c4);
    short4v sv; sv.x = bfb(v.x); sv.y = bfb(v.y); sv.z = bfb(v.z); sv.w = bfb(v.w);
    *(short4v*)&xs[r][c4] = sv;
  }
  __syncthreads();

  short8v af[4];
#pragma unroll
  for (int kk = 0; kk < 4; ++kk)
    af[kk] = *(const short8v*)&xs[wave * 16 + ln15][kk * 32 + g * 8];

  const float* bs[3] = {bq, bk, bv};

  // per-thread row -> (bb, nn) hoisted (row independent of cb)
  int bbv[4], nnv[4];
#pragma unroll
  for (int r = 0; r < 4; ++r) {
    const long row = rowBase + wave * 16 + g * 4 + r;
    bbv[r] = (int)(row / N_);
    nnv[r] = (int)(row - (long)bbv[r] * N_);
  }

#pragma unroll
  for (int m = 0; m < 3; ++m) {
    const short* Wt = wt + (size_t)m * 16384;
    f32x4 acc[8];
#pragma unroll
    for (int cb = 0; cb < 8; ++cb) acc[cb] = (f32x4){0.f, 0.f, 0.f, 0.f};

#pragma unroll
    for (int kk = 0; kk < 4; ++kk) {
#pragma unroll
      for (int cb = 0; cb < 8; ++cb) {
        const short8v bfr =
            *(const short8v*)(Wt + (cb * 16 + ln15) * 128 + kk * 32 + g * 8);
        acc[cb] = __builtin_amdgcn_mfma_f32_16x16x32_bf16(af[kk], bfr, acc[cb], 0, 0, 0);
      }
    }

    const float* bias = bs[m];
#pragma unroll
    for (int cb = 0; cb < 8; ++cb) {
      const int col = cb * 16 + ln15;
      const float bv_ = bias[col];
#pragma unroll
      for (int r = 0; r < 4; ++r) {
        const float val = acc[cb][r] + bv_;
        if (m == 0) {
          const long row = rowBase + wave * 16 + g * 4 + r;
          Q[row * 128 + col] = val;
        } else {
          kv8[(((size_t)nnv[r] * 4 + bbv[r]) << 8) + (m - 1) * 128 + col] = f2fp8(val);
        }
      }
    }
  }
}

// ---------------------------------------------------------------------------
// CSR build
// ---------------------------------------------------------------------------
__global__ __launch_bounds__(256) void csr_hist(const int* __restrict__ ei,
                                                int* __restrict__ cnt) {
  const int e = blockIdx.x * 256 + threadIdx.x;
  if (e < E_) atomicAdd(&cnt[ei[E_ + e]], 1);
}

__global__ __launch_bounds__(1024) void csr_scan(const int* __restrict__ cnt,
                                                 int* __restrict__ rowptr,
                                                 int* __restrict__ fill) {
  __shared__ int part[1024];
  const int t = threadIdx.x;
  int local[10];
  int sum = 0;
#pragma unroll
  for (int i = 0; i < 10; ++i) {
    const int idx = t * 10 + i;
    local[i] = sum;
    sum += (idx < N_) ? cnt[idx] : 0;
  }
  part[t] = sum;
  __syncthreads();
  for (int off = 1; off < 1024; off <<= 1) {
    const int v = (t >= off) ? part[t - off] : 0;
    __syncthreads();
    part[t] += v;
    __syncthreads();
  }
  const int excl = (t == 0) ? 0 : part[t - 1];
#pragma unroll
  for (int i = 0; i < 10; ++i) {
    const int idx = t * 10 + i;
    if (idx <= N_) {
      const int o = excl + local[i];
      rowptr[idx] = o;
      if (idx < N_) fill[idx] = o;
    }
  }
}

// scatter: CSR-ordered src + CSR-ordered copy of edge_attr
__global__ __launch_bounds__(256) void csr_scatter(
    const int* __restrict__ ei, const float* __restrict__ ea,
    int* __restrict__ fill, int* __restrict__ esrc, float* __restrict__ eas) {
  const int e = blockIdx.x * 256 + threadIdx.x;
  if (e < E_) {
    const int dst = ei[E_ + e];
    const int pos = atomicAdd(&fill[dst], 1);
    esrc[pos] = ei[e];
    const float4* s4 = (const float4*)(ea + (size_t)e * 16);
    float4* d4 = (float4*)(eas + (size_t)pos * 16);
    d4[0] = s4[0]; d4[1] = s4[1]; d4[2] = s4[2]; d4[3] = s4[3];
  }
}

// ---------------------------------------------------------------------------
// K2: fused FiLM + logits + softmax + aggregation.
// block per node; wave = head h; lane = 4*p + b  (p = dim-pair 0..15, b = batch).
// K,V gathered as fp8 (ushort = 2 cols), decoded via v_cvt_pk_f32_fp8.
// FiLM once per edge (j-partials across b-lanes, shfl_xor 1,2);
// logit reduce over p-lanes (shfl_xor 4,8,16,32). No LDS, no barriers.
// Single-pass softmax (no max): acc=sum(ex*V), se=sum(ex); agg=acc/se.
// Edge loop unrolled x4 with batched load issue.
// ---------------------------------------------------------------------------
__device__ __forceinline__ void edge_step(
    const float4 ev, const unsigned short ku, const unsigned short vu,
    const float2 q2, const float2* wg, const float2* wb,
    const float bg0, const float bg1, const float bb0, const float bb1,
    float& acc0, float& acc1, float& se) {
  float g0 = ev.x * wg[0].x, g1 = ev.x * wg[0].y;
  float t0 = ev.x * wb[0].x, t1 = ev.x * wb[0].y;
  g0 = fmaf(ev.y, wg[1].x, g0); g1 = fmaf(ev.y, wg[1].y, g1);
  t0 = fmaf(ev.y, wb[1].x, t0); t1 = fmaf(ev.y, wb[1].y, t1);
  g0 = fmaf(ev.z, wg[2].x, g0); g1 = fmaf(ev.z, wg[2].y, g1);
  t0 = fmaf(ev.z, wb[2].x, t0); t1 = fmaf(ev.z, wb[2].y, t1);
  g0 = fmaf(ev.w, wg[3].x, g0); g1 = fmaf(ev.w, wg[3].y, g1);
  t0 = fmaf(ev.w, wb[3].x, t0); t1 = fmaf(ev.w, wb[3].y, t1);
  g0 += __shfl_xor(g0, 1); g1 += __shfl_xor(g1, 1);
  t0 += __shfl_xor(t0, 1); t1 += __shfl_xor(t1, 1);
  g0 += __shfl_xor(g0, 2); g1 += __shfl_xor(g1, 2);
  t0 += __shfl_xor(t0, 2); t1 += __shfl_xor(t1, 2);
  g0 += bg0; g1 += bg1;
  t0 += bb0; t1 += bb1;
  const f32x2 kk = fp8x2f(ku);
  const f32x2 vv = fp8x2f(vu);
  float pl = fmaf(q2.x, fmaf(kk.x, g0, t0), q2.y * fmaf(kk.y, g1, t1));
  pl += __shfl_xor(pl, 4);
  pl += __shfl_xor(pl, 8);
  pl += __shfl_xor(pl, 16);
  pl += __shfl_xor(pl, 32);
  const float ex = __expf(pl * 0.17677669529663687f);  // 1/sqrt(32)
  se += ex;
  acc0 = fmaf(ex, vv.x, acc0);
  acc1 = fmaf(ex, vv.y, acc1);
}

__global__ __launch_bounds__(256) void fused_attn(
    const int* __restrict__ rowptr, const int* __restrict__ esrc,
    const float* __restrict__ eas, const float* __restrict__ Wf,
    const float* __restrict__ bf, const float* __restrict__ Q,
    const unsigned char* __restrict__ kv8, float* __restrict__ agg) {
  const int node = blockIdx.x;
  const int h    = threadIdx.x >> 6;   // wave = head
  const int lane = threadIdx.x & 63;
  const int b    = lane & 3;           // batch
  const int p    = lane >> 2;          // dim-pair within head
  const int col0 = h * 32 + 2 * p;

  // Wf slice: rows j in [4b, 4b+4), gamma cols {col0,col0+1}, beta cols {128+col0,...}
  float2 wg[4], wb[4];
#pragma unroll
  for (int jj = 0; jj < 4; ++jj) {
    wg[jj] = *(const float2*)(Wf + (4 * b + jj) * 256 + col0);
    wb[jj] = *(const float2*)(Wf + (4 * b + jj) * 256 + 128 + col0);
  }
  const float bg0 = 1.f + bf[col0], bg1 = 1.f + bf[col0 + 1];
  const float bb0 = bf[128 + col0], bb1 = bf[129 + col0];

  const float2 q2 = *(const float2*)(Q + ((size_t)b * N_ + node) * 128 + col0);

  const int beg = rowptr[node], end = rowptr[node + 1];
  float acc0 = 0.f, acc1 = 0.f, se = 0.f;

  int i = beg;
  for (; i + 4 <= end; i += 4) {
    const int s0 = esrc[i + 0];
    const int s1 = esrc[i + 1];
    const int s2 = esrc[i + 2];
    const int s3 = esrc[i + 3];
    const float4 e0 = *(const float4*)(eas + (size_t)(i + 0) * 16 + 4 * b);
    const float4 e1 = *(const float4*)(eas + (size_t)(i + 1) * 16 + 4 * b);
    const float4 e2 = *(const float4*)(eas + (size_t)(i + 2) * 16 + 4 * b);
    const float4 e3 = *(const float4*)(eas + (size_t)(i + 3) * 16 + 4 * b);
    const unsigned char* kp0 = kv8 + ((((size_t)s0 << 2) + b) << 8) + col0;
    const unsigned char* kp1 = kv8 + ((((size_t)s1 << 2) + b) << 8) + col0;
    const unsigned char* kp2 = kv8 + ((((size_t)s2 << 2) + b) << 8) + col0;
    const unsigned char* kp3 = kv8 + ((((size_t)s3 << 2) + b) << 8) + col0;
    const unsigned short kk0 = *(const unsigned short*)kp0;
    const unsigned short vv0 = *(const unsigned short*)(kp0 + 128);
    const unsigned short kk1 = *(const unsigned short*)kp1;
    const unsigned short vv1 = *(const unsigned short*)(kp1 + 128);
    const unsigned short kk2 = *(const unsigned short*)kp2;
    const unsigned short vv2 = *(const unsigned short*)(kp2 + 128);
    const unsigned short kk3 = *(const unsigned short*)kp3;
    const unsigned short vv3 = *(const unsigned short*)(kp3 + 128);

    edge_step(e0, kk0, vv0, q2, wg, wb, bg0, bg1, bb0, bb1, acc0, acc1, se);
    edge_step(e1, kk1, vv1, q2, wg, wb, bg0, bg1, bb0, bb1, acc0, acc1, se);
    edge_step(e2, kk2, vv2, q2, wg, wb, bg0, bg1, bb0, bb1, acc0, acc1, se);
    edge_step(e3, kk3, vv3, q2, wg, wb, bg0, bg1, bb0, bb1, acc0, acc1, se);
  }
  for (; i < end; ++i) {
    const int s0 = esrc[i];
    const float4 e0 = *(const float4*)(eas + (size_t)i * 16 + 4 * b);
    const unsigned char* kp0 = kv8 + ((((size_t)s0 << 2) + b) << 8) + col0;
    const unsigned short kk0 = *(const unsigned short*)kp0;
    const unsigned short vv0 = *(const unsigned short*)(kp0 + 128);
    edge_step(e0, kk0, vv0, q2, wg, wb, bg0, bg1, bb0, bb1, acc0, acc1, se);
  }

  const float inv = (end > beg) ? 1.f / se : 0.f;
  float2 o; o.x = acc0 * inv; o.y = acc1 * inv;
  *(float2*)(agg + ((size_t)b * N_ + node) * 128 + col0) = o;
}

// ---------------------------------------------------------------------------
// K4: y = agg @ Wo + bo (MFMA); h = x + y; LayerNorm(h) -> out
// ---------------------------------------------------------------------------
__global__ __launch_bounds__(256) void out_ln_mfma(
    const float* __restrict__ agg, const short* __restrict__ wto,
    const float* __restrict__ bo, const float* __restrict__ x,
    const float* __restrict__ lng, const float* __restrict__ lnb,
    float* __restrict__ out) {
  __shared__ short as_[64][136];
  const int tid  = threadIdx.x;
  const int lane = tid & 63;
  const int wave = tid >> 6;
  const int ln15 = lane & 15;
  const int g    = lane >> 4;
  const long rowBase = (long)blockIdx.x * 64;

  for (int i = tid; i < 64 * 32; i += 256) {
    const int r  = i >> 5;
    const int c4 = (i & 31) * 4;
    const float4 v = *(const float4*)(agg + (rowBase + r) * 128 + c4);
    short4v sv; sv.x = bfb(v.x); sv.y = bfb(v.y); sv.z = bfb(v.z); sv.w = bfb(v.w);
    *(short4v*)&as_[r][c4] = sv;
  }
  __syncthreads();

  short8v af[4];
#pragma unroll
  for (int kk = 0; kk < 4; ++kk)
    af[kk] = *(const short8v*)&as_[wave * 16 + ln15][kk * 32 + g * 8];

  f32x4 acc[8];
#pragma unroll
  for (int cb = 0; cb < 8; ++cb) acc[cb] = (f32x4){0.f, 0.f, 0.f, 0.f};

#pragma unroll
  for (int kk = 0; kk < 4; ++kk) {
#pragma unroll
    for (int cb = 0; cb < 8; ++cb) {
      const short8v bfr =
          *(const short8v*)(wto + (cb * 16 + ln15) * 128 + kk * 32 + g * 8);
      acc[cb] = __builtin_amdgcn_mfma_f32_16x16x32_bf16(af[kk], bfr, acc[cb], 0, 0, 0);
    }
  }

#pragma unroll
  for (int cb = 0; cb < 8; ++cb) {
    const int col = cb * 16 + ln15;
    const float bov = bo[col];
#pragma unroll
    for (int r = 0; r < 4; ++r) {
      const long row = rowBase + wave * 16 + g * 4 + r;
      acc[cb][r] += bov + x[row * 128 + col];
    }
  }

  float s1[4], s2[4];
#pragma unroll
  for (int r = 0; r < 4; ++r) {
    s1[r] = 0.f; s2[r] = 0.f;
#pragma unroll
    for (int cb = 0; cb < 8; ++cb) {
      s1[r] += acc[cb][r];
      s2[r] = fmaf(acc[cb][r], acc[cb][r], s2[r]);
    }
  }
#pragma unroll
  for (int m = 1; m < 16; m <<= 1) {
#pragma unroll
    for (int r = 0; r < 4; ++r) {
      s1[r] += __shfl_xor(s1[r], m);
      s2[r] += __shfl_xor(s2[r], m);
    }
  }
  float mu[4], inv[4];
#pragma unroll
  for (int r = 0; r < 4; ++r) {
    mu[r] = s1[r] * (1.f / 128.f);
    const float var = s2[r] * (1.f / 128.f) - mu[r] * mu[r];
    inv[r] = rsqrtf(var + 1e-5f);
  }

#pragma unroll
  for (int cb = 0; cb < 8; ++cb) {
    const int col = cb * 16 + ln15;
    const float gv = lng[col], bv_ = lnb[col];
#pragma unroll
    for (int r = 0; r < 4; ++r) {
      const long row = rowBase + wave * 16 + g * 4 + r;
      out[row * 128 + col] = (acc[cb][r] - mu[r]) * inv[r] * gv + bv_;
    }
  }
}

// ---------------------------------------------------------------------------
extern "C" void kernel_launch(void* const* d_in, const int* in_sizes, int n_in,
                              void* d_out, int out_size, void* d_ws, size_t ws_size,
                              hipStream_t stream) {
  const float* x   = (const float*)d_in[0];
  const int*   ei  = (const int*)d_in[1];
  const float* ea  = (const float*)d_in[2];
  const float* Wq  = (const float*)d_in[3];
  const float* bq  = (const float*)d_in[4];
  const float* Wk  = (const float*)d_in[5];
  const float* bk  = (const float*)d_in[6];
  const float* Wv  = (const float*)d_in[7];
  const float* bv  = (const float*)d_in[8];
  const float* Wf  = (const float*)d_in[9];
  const float* bf  = (const float*)d_in[10];
  const float* Wo  = (const float*)d_in[11];
  const float* bo  = (const float*)d_in[12];
  const float* lng = (const float*)d_in[13];
  const float* lnb = (const float*)d_in[14];
  float* out = (float*)d_out;

  const size_t NQ = (size_t)B_ * N_ * HID_;  // 5,120,000

  char* base = (char*)d_ws;
  size_t off = 0;
  float* Q    = (float*)(base + off); off += NQ * 4;                 // 20.48MB
  float* agg  = (float*)(base + off); off += NQ * 4;                 // 20.48MB
  float* eas  = (float*)(base + off); off += (size_t)E_ * 16 * 4;    // 10.24MB
  unsigned char* kv8 = (unsigned char*)(base + off);
  off += (size_t)B_ * N_ * 256;                                      // 10.24MB
  short* wt   = (short*)(base + off); off += 4 * 16384 * 2;          // 128KB
  int*  cnt    = (int*)(base + off); off += N_ * 4;
  int*  rowptr = (int*)(base + off); off += (N_ + 1) * 4;
  int*  fill   = (int*)(base + off); off += N_ * 4;
  int*  esrc   = (int*)(base + off); off += E_ * 4;

  hipMemsetAsync(cnt, 0, N_ * sizeof(int), stream);

  wt_prep<<<256, 256, 0, stream>>>(Wq, Wk, Wv, Wo, wt);
  qkv_mfma<<<(B_ * N_) / 64, 256, 0, stream>>>(x, wt, bq, bk, bv, Q, kv8);
  csr_hist<<<(E_ + 255) / 256, 256, 0, stream>>>(ei, cnt);
  csr_scan<<<1, 1024, 0, stream>>>(cnt, rowptr, fill);
  csr_scatter<<<(E_ + 255) / 256, 256, 0, stream>>>(ei, ea, fill, esrc, eas);
  fused_attn<<<N_, 256, 0, stream>>>(rowptr, esrc, eas, Wf, bf, Q, kv8, agg);
  out_ln_mfma<<<(B_ * N_) / 64, 256, 0, stream>>>(agg, wt + 3 * 16384, bo, x, lng, lnb, out);
}

// Round 10
// 214.037 us; speedup vs baseline: 1.3459x; 1.0036x over previous
//
#include <hip/hip_runtime.h>
#include <hip/hip_bf16.h>

#define B_ 4
#define N_ 10000
#define E_ 160000
#define D_ 128
#define H_ 4
#define HID_ 128
#define DK_ 32
#define DE_ 16
#define NPB 4   // nodes per block in fused_attn

typedef __attribute__((ext_vector_type(8))) short short8v;
typedef __attribute__((ext_vector_type(4))) short short4v;
typedef __attribute__((ext_vector_type(4))) float f32x4;
typedef __attribute__((ext_vector_type(2))) float f32x2;

// fp32 -> bf16 bits, round-to-nearest-even
__device__ __forceinline__ short bfb(float f) {
  union { float f; unsigned u; } c; c.f = f;
  unsigned u = c.u + 0x7FFFu + ((c.u >> 16) & 1u);
  return (short)(u >> 16);
}

// fp32 -> fp8 e4m3 (OCP on gfx950)
__device__ __forceinline__ unsigned char f2fp8(float f) {
  int r = __builtin_amdgcn_cvt_pk_fp8_f32(f, f, 0, false);
  return (unsigned char)(r & 0xff);
}
// 2 packed fp8 -> 2 fp32
__device__ __forceinline__ f32x2 fp8x2f(unsigned short u) {
  return __builtin_amdgcn_cvt_pk_f32_fp8((int)u, false);
}

// ---------------------------------------------------------------------------
// P0: W^T bf16 prep. wt[m][n][k] = bf16(W_m[k*128+n]),  m: 0=q 1=k 2=v 3=o
// ---------------------------------------------------------------------------
__global__ __launch_bounds__(256) void wt_prep(
    const float* __restrict__ Wq, const float* __restrict__ Wk,
    const float* __restrict__ Wv, const float* __restrict__ Wo,
    short* __restrict__ wt) {
  const float* Ws[4] = {Wq, Wk, Wv, Wo};
  const int i = blockIdx.x * 256 + threadIdx.x;   // 0..65535
  const int m = i >> 14;
  const int k = (i >> 7) & 127;
  const int n = i & 127;
  wt[(size_t)m * 16384 + n * 128 + k] = bfb(Ws[m][k * 128 + n]);
}

// ---------------------------------------------------------------------------
// K1: QKV projection via MFMA. block = 256 (4 waves), 64 rows/block.
// Q -> fp32 [b][n][128]; K,V -> fp8 e4m3 kv8[n][b][0:128 = K | 128:256 = V]
// ---------------------------------------------------------------------------
__global__ __launch_bounds__(256) void qkv_mfma(
    const float* __restrict__ x, const short* __restrict__ wt,
    const float* __restrict__ bq, const float* __restrict__ bk,
    const float* __restrict__ bv,
    float* __restrict__ Q, unsigned char* __restrict__ kv8) {
  __shared__ short xs[64][136];
  const int tid  = threadIdx.x;
  const int lane = tid & 63;
  const int wave = tid >> 6;
  const int ln15 = lane & 15;
  const int g    = lane >> 4;
  const long rowBase = (long)blockIdx.x * 64;

  for (int i = tid; i < 64 * 32; i += 256) {
    const int r  = i >> 5;
    const int c4 = (i & 31) * 4;
    const float4 v = *(const float4*)(x + (rowBase + r) * 128 + c4);
    short4v sv; sv.x = bfb(v.x); sv.y = bfb(v.y); sv.z = bfb(v.z); sv.w = bfb(v.w);
    *(short4v*)&xs[r][c4] = sv;
  }
  __syncthreads();

  short8v af[4];
#pragma unroll
  for (int kk = 0; kk < 4; ++kk)
    af[kk] = *(const short8v*)&xs[wave * 16 + ln15][kk * 32 + g * 8];

  const float* bs[3] = {bq, bk, bv};

  int bbv[4], nnv[4];
#pragma unroll
  for (int r = 0; r < 4; ++r) {
    const long row = rowBase + wave * 16 + g * 4 + r;
    bbv[r] = (int)(row / N_);
    nnv[r] = (int)(row - (long)bbv[r] * N_);
  }

#pragma unroll
  for (int m = 0; m < 3; ++m) {
    const short* Wt = wt + (size_t)m * 16384;
    f32x4 acc[8];
#pragma unroll
    for (int cb = 0; cb < 8; ++cb) acc[cb] = (f32x4){0.f, 0.f, 0.f, 0.f};

#pragma unroll
    for (int kk = 0; kk < 4; ++kk) {
#pragma unroll
      for (int cb = 0; cb < 8; ++cb) {
        const short8v bfr =
            *(const short8v*)(Wt + (cb * 16 + ln15) * 128 + kk * 32 + g * 8);
        acc[cb] = __builtin_amdgcn_mfma_f32_16x16x32_bf16(af[kk], bfr, acc[cb], 0, 0, 0);
      }
    }

    const float* bias = bs[m];
#pragma unroll
    for (int cb = 0; cb < 8; ++cb) {
      const int col = cb * 16 + ln15;
      const float bv_ = bias[col];
#pragma unroll
      for (int r = 0; r < 4; ++r) {
        const float val = acc[cb][r] + bv_;
        if (m == 0) {
          const long row = rowBase + wave * 16 + g * 4 + r;
          Q[row * 128 + col] = val;
        } else {
          kv8[(((size_t)nnv[r] * 4 + bbv[r]) << 8) + (m - 1) * 128 + col] = f2fp8(val);
        }
      }
    }
  }
}

// ---------------------------------------------------------------------------
// CSR build
// ---------------------------------------------------------------------------
__global__ __launch_bounds__(256) void csr_hist(const int* __restrict__ ei,
                                                int* __restrict__ cnt) {
  const int e = blockIdx.x * 256 + threadIdx.x;
  if (e < E_) atomicAdd(&cnt[ei[E_ + e]], 1);
}

__global__ __launch_bounds__(1024) void csr_scan(const int* __restrict__ cnt,
                                                 int* __restrict__ rowptr,
                                                 int* __restrict__ fill) {
  __shared__ int part[1024];
  const int t = threadIdx.x;
  int local[10];
  int sum = 0;
#pragma unroll
  for (int i = 0; i < 10; ++i) {
    const int idx = t * 10 + i;
    local[i] = sum;
    sum += (idx < N_) ? cnt[idx] : 0;
  }
  part[t] = sum;
  __syncthreads();
  for (int off = 1; off < 1024; off <<= 1) {
    const int v = (t >= off) ? part[t - off] : 0;
    __syncthreads();
    part[t] += v;
    __syncthreads();
  }
  const int excl = (t == 0) ? 0 : part[t - 1];
#pragma unroll
  for (int i = 0; i < 10; ++i) {
    const int idx = t * 10 + i;
    if (idx <= N_) {
      const int o = excl + local[i];
      rowptr[idx] = o;
      if (idx < N_) fill[idx] = o;
    }
  }
}

// scatter: CSR-ordered src + CSR-ordered copy of edge_attr
__global__ __launch_bounds__(256) void csr_scatter(
    const int* __restrict__ ei, const float* __restrict__ ea,
    int* __restrict__ fill, int* __restrict__ esrc, float* __restrict__ eas) {
  const int e = blockIdx.x * 256 + threadIdx.x;
  if (e < E_) {
    const int dst = ei[E_ + e];
    const int pos = atomicAdd(&fill[dst], 1);
    esrc[pos] = ei[e];
    const float4* s4 = (const float4*)(ea + (size_t)e * 16);
    float4* d4 = (float4*)(eas + (size_t)pos * 16);
    d4[0] = s4[0]; d4[1] = s4[1]; d4[2] = s4[2]; d4[3] = s4[3];
  }
}

// ---------------------------------------------------------------------------
// K2: fused FiLM + logits + softmax + aggregation.
// block = NPB nodes; wave = head h; lane = 4*p + b.
// Wf register slices loaded ONCE per block (amortized over NPB nodes).
// Edge loop unrolled x8 with batched load issue (deep MLP).
// FiLM once per edge (j-partials across b-lanes, shfl_xor 1,2);
// logit reduce over p-lanes (shfl_xor 4,8,16,32).
// Single-pass softmax (no max): acc=sum(ex*V), se=sum(ex); agg=acc/se.
// ---------------------------------------------------------------------------
__device__ __forceinline__ void edge_step(
    const float4 ev, const unsigned short ku, const unsigned short vu,
    const float2 q2, const float2* wg, const float2* wb,
    const float bg0, const float bg1, const float bb0, const float bb1,
    float& acc0, float& acc1, float& se) {
  float g0 = ev.x * wg[0].x, g1 = ev.x * wg[0].y;
  float t0 = ev.x * wb[0].x, t1 = ev.x * wb[0].y;
  g0 = fmaf(ev.y, wg[1].x, g0); g1 = fmaf(ev.y, wg[1].y, g1);
  t0 = fmaf(ev.y, wb[1].x, t0); t1 = fmaf(ev.y, wb[1].y, t1);
  g0 = fmaf(ev.z, wg[2].x, g0); g1 = fmaf(ev.z, wg[2].y, g1);
  t0 = fmaf(ev.z, wb[2].x, t0); t1 = fmaf(ev.z, wb[2].y, t1);
  g0 = fmaf(ev.w, wg[3].x, g0); g1 = fmaf(ev.w, wg[3].y, g1);
  t0 = fmaf(ev.w, wb[3].x, t0); t1 = fmaf(ev.w, wb[3].y, t1);
  g0 += __shfl_xor(g0, 1); g1 += __shfl_xor(g1, 1);
  t0 += __shfl_xor(t0, 1); t1 += __shfl_xor(t1, 1);
  g0 += __shfl_xor(g0, 2); g1 += __shfl_xor(g1, 2);
  t0 += __shfl_xor(t0, 2); t1 += __shfl_xor(t1, 2);
  g0 += bg0; g1 += bg1;
  t0 += bb0; t1 += bb1;
  const f32x2 kk = fp8x2f(ku);
  const f32x2 vv = fp8x2f(vu);
  float pl = fmaf(q2.x, fmaf(kk.x, g0, t0), q2.y * fmaf(kk.y, g1, t1));
  pl += __shfl_xor(pl, 4);
  pl += __shfl_xor(pl, 8);
  pl += __shfl_xor(pl, 16);
  pl += __shfl_xor(pl, 32);
  const float ex = __expf(pl * 0.17677669529663687f);  // 1/sqrt(32)
  se += ex;
  acc0 = fmaf(ex, vv.x, acc0);
  acc1 = fmaf(ex, vv.y, acc1);
}

__global__ __launch_bounds__(256) void fused_attn(
    const int* __restrict__ rowptr, const int* __restrict__ esrc,
    const float* __restrict__ eas, const float* __restrict__ Wf,
    const float* __restrict__ bf, const float* __restrict__ Q,
    const unsigned char* __restrict__ kv8, float* __restrict__ agg) {
  const int h    = threadIdx.x >> 6;   // wave = head
  const int lane = threadIdx.x & 63;
  const int b    = lane & 3;           // batch
  const int p    = lane >> 2;          // dim-pair within head
  const int col0 = h * 32 + 2 * p;

  // Wf slice: rows j in [4b, 4b+4), gamma cols {col0,col0+1}, beta cols {128+col0,...}
  float2 wg[4], wb[4];
#pragma unroll
  for (int jj = 0; jj < 4; ++jj) {
    wg[jj] = *(const float2*)(Wf + (4 * b + jj) * 256 + col0);
    wb[jj] = *(const float2*)(Wf + (4 * b + jj) * 256 + 128 + col0);
  }
  const float bg0 = 1.f + bf[col0], bg1 = 1.f + bf[col0 + 1];
  const float bb0 = bf[128 + col0], bb1 = bf[129 + col0];

  for (int nn = 0; nn < NPB; ++nn) {
    const int node = blockIdx.x * NPB + nn;
    const float2 q2 = *(const float2*)(Q + ((size_t)b * N_ + node) * 128 + col0);
    const int beg = rowptr[node], end = rowptr[node + 1];
    float acc0 = 0.f, acc1 = 0.f, se = 0.f;

    int i = beg;
    for (; i + 8 <= end; i += 8) {
      int s[8];
#pragma unroll
      for (int u = 0; u < 8; ++u) s[u] = esrc[i + u];
      float4 e[8];
#pragma unroll
      for (int u = 0; u < 8; ++u)
        e[u] = *(const float4*)(eas + (size_t)(i + u) * 16 + 4 * b);
      unsigned short kk[8], vv[8];
#pragma unroll
      for (int u = 0; u < 8; ++u) {
        const unsigned char* kp = kv8 + ((((size_t)s[u] << 2) + b) << 8) + col0;
        kk[u] = *(const unsigned short*)kp;
        vv[u] = *(const unsigned short*)(kp + 128);
      }
#pragma unroll
      for (int u = 0; u < 8; ++u)
        edge_step(e[u], kk[u], vv[u], q2, wg, wb, bg0, bg1, bb0, bb1, acc0, acc1, se);
    }
    for (; i < end; ++i) {
      const int s0 = esrc[i];
      const float4 e0 = *(const float4*)(eas + (size_t)i * 16 + 4 * b);
      const unsigned char* kp0 = kv8 + ((((size_t)s0 << 2) + b) << 8) + col0;
      const unsigned short kk0 = *(const unsigned short*)kp0;
      const unsigned short vv0 = *(const unsigned short*)(kp0 + 128);
      edge_step(e0, kk0, vv0, q2, wg, wb, bg0, bg1, bb0, bb1, acc0, acc1, se);
    }

    const float inv = (end > beg) ? 1.f / se : 0.f;
    float2 o; o.x = acc0 * inv; o.y = acc1 * inv;
    *(float2*)(agg + ((size_t)b * N_ + node) * 128 + col0) = o;
  }
}

// ---------------------------------------------------------------------------
// K4: y = agg @ Wo + bo (MFMA); h = x + y; LayerNorm(h) -> out
// ---------------------------------------------------------------------------
__global__ __launch_bounds__(256) void out_ln_mfma(
    const float* __restrict__ agg, const short* __restrict__ wto,
    const float* __restrict__ bo, const float* __restrict__ x,
    const float* __restrict__ lng, const float* __restrict__ lnb,
    float* __restrict__ out) {
  __shared__ short as_[64][136];
  const int tid  = threadIdx.x;
  const int lane = tid & 63;
  const int wave = tid >> 6;
  const int ln15 = lane & 15;
  const int g    = lane >> 4;
  const long rowBase = (long)blockIdx.x * 64;

  for (int i = tid; i < 64 * 32; i += 256) {
    const int r  = i >> 5;
    const int c4 = (i & 31) * 4;
    const float4 v = *(const float4*)(agg + (rowBase + r) * 128 + c4);
    short4v sv; sv.x = bfb(v.x); sv.y = bfb(v.y); sv.z = bfb(v.z); sv.w = bfb(v.w);
    *(short4v*)&as_[r][c4] = sv;
  }
  __syncthreads();

  short8v af[4];
#pragma unroll
  for (int kk = 0; kk < 4; ++kk)
    af[kk] = *(const short8v*)&as_[wave * 16 + ln15][kk * 32 + g * 8];

  f32x4 acc[8];
#pragma unroll
  for (int cb = 0; cb < 8; ++cb) acc[cb] = (f32x4){0.f, 0.f, 0.f, 0.f};

#pragma unroll
  for (int kk = 0; kk < 4; ++kk) {
#pragma unroll
    for (int cb = 0; cb < 8; ++cb) {
      const short8v bfr =
          *(const short8v*)(wto + (cb * 16 + ln15) * 128 + kk * 32 + g * 8);
      acc[cb] = __builtin_amdgcn_mfma_f32_16x16x32_bf16(af[kk], bfr, acc[cb], 0, 0, 0);
    }
  }

#pragma unroll
  for (int cb = 0; cb < 8; ++cb) {
    const int col = cb * 16 + ln15;
    const float bov = bo[col];
#pragma unroll
    for (int r = 0; r < 4; ++r) {
      const long row = rowBase + wave * 16 + g * 4 + r;
      acc[cb][r] += bov + x[row * 128 + col];
    }
  }

  float s1[4], s2[4];
#pragma unroll
  for (int r = 0; r < 4; ++r) {
    s1[r] = 0.f; s2[r] = 0.f;
#pragma unroll
    for (int cb = 0; cb < 8; ++cb) {
      s1[r] += acc[cb][r];
      s2[r] = fmaf(acc[cb][r], acc[cb][r], s2[r]);
    }
  }
#pragma unroll
  for (int m = 1; m < 16; m <<= 1) {
#pragma unroll
    for (int r = 0; r < 4; ++r) {
      s1[r] += __shfl_xor(s1[r], m);
      s2[r] += __shfl_xor(s2[r], m);
    }
  }
  float mu[4], inv[4];
#pragma unroll
  for (int r = 0; r < 4; ++r) {
    mu[r] = s1[r] * (1.f / 128.f);
    const float var = s2[r] * (1.f / 128.f) - mu[r] * mu[r];
    inv[r] = rsqrtf(var + 1e-5f);
  }

#pragma unroll
  for (int cb = 0; cb < 8; ++cb) {
    const int col = cb * 16 + ln15;
    const float gv = lng[col], bv_ = lnb[col];
#pragma unroll
    for (int r = 0; r < 4; ++r) {
      const long row = rowBase + wave * 16 + g * 4 + r;
      out[row * 128 + col] = (acc[cb][r] - mu[r]) * inv[r] * gv + bv_;
    }
  }
}

// ---------------------------------------------------------------------------
extern "C" void kernel_launch(void* const* d_in, const int* in_sizes, int n_in,
                              void* d_out, int out_size, void* d_ws, size_t ws_size,
                              hipStream_t stream) {
  const float* x   = (const float*)d_in[0];
  const int*   ei  = (const int*)d_in[1];
  const float* ea  = (const float*)d_in[2];
  const float* Wq  = (const float*)d_in[3];
  const float* bq  = (const float*)d_in[4];
  const float* Wk  = (const float*)d_in[5];
  const float* bk  = (const float*)d_in[6];
  const float* Wv  = (const float*)d_in[7];
  const float* bv  = (const float*)d_in[8];
  const float* Wf  = (const float*)d_in[9];
  const float* bf  = (const float*)d_in[10];
  const float* Wo  = (const float*)d_in[11];
  const float* bo  = (const float*)d_in[12];
  const float* lng = (const float*)d_in[13];
  const float* lnb = (const float*)d_in[14];
  float* out = (float*)d_out;

  const size_t NQ = (size_t)B_ * N_ * HID_;  // 5,120,000

  char* base = (char*)d_ws;
  size_t off = 0;
  float* Q    = (float*)(base + off); off += NQ * 4;                 // 20.48MB
  float* agg  = (float*)(base + off); off += NQ * 4;                 // 20.48MB
  float* eas  = (float*)(base + off); off += (size_t)E_ * 16 * 4;    // 10.24MB
  unsigned char* kv8 = (unsigned char*)(base + off);
  off += (size_t)B_ * N_ * 256;                                      // 10.24MB
  short* wt   = (short*)(base + off); off += 4 * 16384 * 2;          // 128KB
  int*  cnt    = (int*)(base + off); off += N_ * 4;
  int*  rowptr = (int*)(base + off); off += (N_ + 1) * 4;
  int*  fill   = (int*)(base + off); off += N_ * 4;
  int*  esrc   = (int*)(base + off); off += E_ * 4;

  hipMemsetAsync(cnt, 0, N_ * sizeof(int), stream);

  wt_prep<<<256, 256, 0, stream>>>(Wq, Wk, Wv, Wo, wt);
  qkv_mfma<<<(B_ * N_) / 64, 256, 0, stream>>>(x, wt, bq, bk, bv, Q, kv8);
  csr_hist<<<(E_ + 255) / 256, 256, 0, stream>>>(ei, cnt);
  csr_scan<<<1, 1024, 0, stream>>>(cnt, rowptr, fill);
  csr_scatter<<<(E_ + 255) / 256, 256, 0, stream>>>(ei, ea, fill, esrc, eas);
  fused_attn<<<N_ / NPB, 256, 0, stream>>>(rowptr, esrc, eas, Wf, bf, Q, kv8, agg);
  out_ln_mfma<<<(B_ * N_) / 64, 256, 0, stream>>>(agg, wt + 3 * 16384, bo, x, lng, lnb, out);
}